// Round 1
// baseline (533.374 us; speedup 1.0000x reference)
//
#include <hip/hip_runtime.h>
#include <math.h>

#define NN 10000
#define NE 160000

// ---------------- CSR build ----------------

__global__ __launch_bounds__(256) void deg_kernel(const int* __restrict__ src,
                                                  const int* __restrict__ dst,
                                                  int* __restrict__ deg,
                                                  int* __restrict__ cnt, int E) {
  int e = blockIdx.x * 256 + threadIdx.x;
  if (e < E) {
    atomicAdd(&deg[src[e]], 1);
    atomicAdd(&cnt[dst[e]], 1);
  }
}

__global__ __launch_bounds__(256) void dinv_kernel(const int* __restrict__ deg,
                                                   float* __restrict__ dinv, int n) {
  int i = blockIdx.x * 256 + threadIdx.x;
  if (i < n) {
    int d = deg[i];
    dinv[i] = d > 0 ? 1.0f / sqrtf((float)d) : 0.0f;
  }
}

// single-block exclusive scan over n<=10240 counts
__global__ __launch_bounds__(1024) void scan_kernel(const int* __restrict__ cnt,
                                                    int* __restrict__ off, int n) {
  __shared__ int sh[1024];
  int t = threadIdx.x;
  int per = (n + 1023) / 1024;
  int base = t * per;
  int sum = 0;
  for (int i = 0; i < per; i++) {
    int idx = base + i;
    if (idx < n) sum += cnt[idx];
  }
  sh[t] = sum;
  __syncthreads();
  for (int d = 1; d < 1024; d <<= 1) {
    int v = (t >= d) ? sh[t - d] : 0;
    __syncthreads();
    if (t >= d) sh[t] += v;
    __syncthreads();
  }
  int run = (t > 0) ? sh[t - 1] : 0;
  for (int i = 0; i < per; i++) {
    int idx = base + i;
    if (idx < n) { off[idx] = run; run += cnt[idx]; }
  }
  if (t == 0) off[n] = sh[1023];
}

__global__ __launch_bounds__(256) void fill_kernel(const int* __restrict__ src,
                                                   const int* __restrict__ dst,
                                                   const float* __restrict__ dinv,
                                                   const int* __restrict__ off,
                                                   int* __restrict__ pos,
                                                   int* __restrict__ csrc,
                                                   float* __restrict__ cw, int E) {
  int e = blockIdx.x * 256 + threadIdx.x;
  if (e < E) {
    int s = src[e], d = dst[e];
    int slot = off[d] + atomicAdd(&pos[d], 1);
    csrc[slot] = s;
    cw[slot] = -dinv[s] * dinv[d];
  }
}

// ---------------- weight concat for push-through layers ----------------
// Wc [Fin][3*Fp]: cols [0,Fp)=W0-W2, [Fp,2Fp)=W1, [2Fp,3Fp)=W2 ; pad cols (f>=F) zeroed

__global__ __launch_bounds__(256) void wcat_kernel(const float* __restrict__ W,
                                                   float* __restrict__ Wc,
                                                   int Fin, int F, int Fp) {
  int i = blockIdx.x * 256 + threadIdx.x;
  int w3 = 3 * Fp;
  int total = Fin * w3;
  if (i >= total) return;
  int row = i / w3;
  int c = i - row * w3;
  int sec = c / Fp;
  int f = c - sec * Fp;
  float v = 0.0f;
  if (f < F) {
    if (sec == 0)      v = W[row * F + f] - W[2 * Fin * F + row * F + f];
    else if (sec == 1) v = W[Fin * F + row * F + f];
    else               v = W[2 * Fin * F + row * F + f];
  }
  Wc[i] = v;
}

// ---------------- GEMM: Y = X[M x Kd] @ W[Kd x Nd] (+acc)(+bias)(+relu) ----------------
// BM=64, BN=32, BK=16; block (32,8); each thread: 8 rows x 1 col

#define BM 64
#define BN 32
#define BK 16

__global__ __launch_bounds__(256) void gemm_kernel(
    const float* __restrict__ X, int ldx,
    const float* __restrict__ W,               // ld = Nd
    const float* __restrict__ bias,            // nullable
    float* __restrict__ Y, int ldy,
    const float* __restrict__ acc, int lda,    // nullable
    int M, int Kd, int Nd, int relu) {
  __shared__ float Xs[BK][BM + 4];
  __shared__ float Ws[BK][BN];
  int tx = threadIdx.x;            // 0..31 (col)
  int ty = threadIdx.y;            // 0..7
  int tid = ty * 32 + tx;
  int row0 = blockIdx.y * BM;
  int col0 = blockIdx.x * BN;
  int myrow = ty * 8;
  float accv[8] = {0.f, 0.f, 0.f, 0.f, 0.f, 0.f, 0.f, 0.f};

  for (int k0 = 0; k0 < Kd; k0 += BK) {
    // X tile: 64 rows x 16 k (transposed into LDS)
    int kk = tid & 15, rbase = tid >> 4;   // 16 rows per pass, 4 passes
    for (int i = 0; i < 4; i++) {
      int r = rbase + 16 * i;
      int gr = row0 + r, gk = k0 + kk;
      float v = (gr < M && gk < Kd) ? X[(size_t)gr * ldx + gk] : 0.0f;
      Xs[kk][r] = v;
    }
    // W tile: 16 x 32
    int c = tid & 31, k2 = tid >> 5;       // 8 k per pass, 2 passes
    for (int i = 0; i < 2; i++) {
      int kkw = k2 + 8 * i;
      int gk = k0 + kkw, gc = col0 + c;
      Ws[kkw][c] = (gk < Kd && gc < Nd) ? W[(size_t)gk * Nd + gc] : 0.0f;
    }
    __syncthreads();
#pragma unroll
    for (int kk2 = 0; kk2 < BK; kk2++) {
      float wv = Ws[kk2][tx];
      const float4* xp = (const float4*)&Xs[kk2][myrow];
      float4 x0 = xp[0], x1 = xp[1];
      accv[0] += x0.x * wv; accv[1] += x0.y * wv;
      accv[2] += x0.z * wv; accv[3] += x0.w * wv;
      accv[4] += x1.x * wv; accv[5] += x1.y * wv;
      accv[6] += x1.z * wv; accv[7] += x1.w * wv;
    }
    __syncthreads();
  }

  int gc = col0 + tx;
  if (gc < Nd) {
    float b = bias ? bias[gc] : 0.0f;
    for (int m = 0; m < 8; m++) {
      int gr = row0 + myrow + m;
      if (gr < M) {
        float v = accv[m] + b;
        if (acc) v += acc[(size_t)gr * lda + gc];
        if (relu) v = fmaxf(v, 0.0f);
        Y[(size_t)gr * ldy + gc] = v;
      }
    }
  }
}

// ---------------- SpMM (CSR-by-dst gather): Y = alpha * L_hat X + beta * add (+bias)(+relu) ----

__global__ __launch_bounds__(256) void spmm_kernel(
    const int* __restrict__ off,
    const int* __restrict__ csrc,
    const float* __restrict__ cw,
    const float* __restrict__ X, int ldx,
    float* __restrict__ Y, int ldy,
    const float* __restrict__ add, int lda,   // nullable
    const float* __restrict__ bias,           // nullable
    float alpha, float beta,
    int n, int F, int Fstore, int relu) {
  int f4 = threadIdx.x << 2;                  // F is a multiple of 4
  int node = blockIdx.x * blockDim.y + threadIdx.y;
  if (node >= n) return;
  int j0 = off[node], j1 = off[node + 1];
  float sx = 0.f, sy = 0.f, sz = 0.f, sw = 0.f;
  for (int j = j0; j < j1; j++) {
    int sn = csrc[j];
    float w = cw[j];
    float4 xv = *(const float4*)(X + (size_t)sn * ldx + f4);
    sx += w * xv.x; sy += w * xv.y; sz += w * xv.z; sw += w * xv.w;
  }
  float vals[4] = {sx, sy, sz, sw};
#pragma unroll
  for (int c = 0; c < 4; c++) {
    int f = f4 + c;
    if (f < Fstore) {
      float v = alpha * vals[c];
      if (add) v += beta * add[(size_t)node * lda + f];
      if (bias) v += bias[f];
      if (relu) v = fmaxf(v, 0.0f);
      Y[(size_t)node * ldy + f] = v;
    }
  }
}

// ---------------- softmax over last dim (F=19) ----------------

__global__ __launch_bounds__(256) void softmax_kernel(float* __restrict__ Y, int n, int F) {
  int i = blockIdx.x * 256 + threadIdx.x;
  if (i >= n) return;
  float* row = Y + (size_t)i * F;
  float m = row[0];
  for (int f = 1; f < F; f++) m = fmaxf(m, row[f]);
  float s = 0.0f;
  for (int f = 0; f < F; f++) s += expf(row[f] - m);
  float inv = 1.0f / s;
  for (int f = 0; f < F; f++) row[f] = expf(row[f] - m) * inv;
}

// ---------------- host orchestration ----------------

static void gemm(hipStream_t s, const float* X, int ldx, const float* W, int Nd,
                 const float* bias, float* Y, int ldy, const float* acc, int lda,
                 int M, int Kd, int relu) {
  dim3 g((Nd + BN - 1) / BN, (M + BM - 1) / BM), b(32, 8);
  gemm_kernel<<<g, b, 0, s>>>(X, ldx, W, bias, Y, ldy, acc, lda, M, Kd, Nd, relu);
}

static void spmm(hipStream_t s, const int* off, const int* csrc, const float* cw,
                 const float* X, int ldx, float* Y, int ldy,
                 const float* add, int lda, const float* bias,
                 float alpha, float beta, int F, int Fstore, int relu) {
  int bx = F / 4;
  int by = 256 / bx;
  dim3 g((NN + by - 1) / by), b(bx, by);
  spmm_kernel<<<g, b, 0, s>>>(off, csrc, cw, X, ldx, Y, ldy, add, lda, bias,
                              alpha, beta, NN, F, Fstore, relu);
}

extern "C" void kernel_launch(void* const* d_in, const int* in_sizes, int n_in,
                              void* d_out, int out_size, void* d_ws, size_t ws_size,
                              hipStream_t stream) {
  const float* x  = (const float*)d_in[0];
  const int*   ei = (const int*)d_in[1];
  const float* W1 = (const float*)d_in[2];  const float* b1 = (const float*)d_in[3];
  const float* W2 = (const float*)d_in[4];  const float* b2 = (const float*)d_in[5];
  const float* W3 = (const float*)d_in[6];  const float* b3 = (const float*)d_in[7];
  const float* W4 = (const float*)d_in[8];  const float* b4 = (const float*)d_in[9];
  const float* W5 = (const float*)d_in[10]; const float* b5 = (const float*)d_in[11];
  float* out = (float*)d_out;
  const int* src = ei;
  const int* dst = ei + NE;

  char* p = (char*)d_ws;
  auto alloc = [&](size_t bytes) {
    char* r = p;
    p += (bytes + 255) & ~(size_t)255;
    return r;
  };
  int*   i_deg  = (int*)alloc(sizeof(int) * NN * 3);   // deg, cnt, pos contiguous (one memset)
  int*   i_cnt  = i_deg + NN;
  int*   i_pos  = i_cnt + NN;
  float* f_dinv = (float*)alloc(sizeof(float) * NN);
  int*   i_off  = (int*)alloc(sizeof(int) * (NN + 1));
  int*   i_csrc = (int*)alloc(sizeof(int) * NE);
  float* f_cw   = (float*)alloc(sizeof(float) * NE);
  float* bufP   = (float*)alloc(sizeof(float) * NN * 64);
  float* bufQ   = (float*)alloc(sizeof(float) * NN * 128);
  float* bufR   = (float*)alloc(sizeof(float) * NN * 64);
  float* bufS   = (float*)alloc(sizeof(float) * NN * 128);
  float* wc1    = (float*)alloc(sizeof(float) * 782 * 48);
  float* wc5    = (float*)alloc(sizeof(float) * 128 * 60);
  (void)ws_size; (void)in_sizes; (void)n_in; (void)out_size;

  // ---- graph structure (rebuilt every call; ws is re-poisoned) ----
  hipMemsetAsync(i_deg, 0, sizeof(int) * NN * 3, stream);
  deg_kernel<<<(NE + 255) / 256, 256, 0, stream>>>(src, dst, i_deg, i_cnt, NE);
  dinv_kernel<<<(NN + 255) / 256, 256, 0, stream>>>(i_deg, f_dinv, NN);
  scan_kernel<<<1, 1024, 0, stream>>>(i_cnt, i_off, NN);
  fill_kernel<<<(NE + 255) / 256, 256, 0, stream>>>(src, dst, f_dinv, i_off, i_pos,
                                                    i_csrc, f_cw, NE);
  wcat_kernel<<<(782 * 48 + 255) / 256, 256, 0, stream>>>(W1, wc1, 782, 16, 16);
  wcat_kernel<<<(128 * 60 + 255) / 256, 256, 0, stream>>>(W5, wc5, 128, 19, 20);

  // ---- Layer 1 (push-through): Fin=782, F=16 ----
  // ABC = X @ Wc1  -> bufQ (ld48): A=+0, B=+16, C=+32
  gemm(stream, x, 782, wc1, 48, nullptr, bufQ, 48, nullptr, 0, NN, 782, 0);
  // D = L C
  spmm(stream, i_off, i_csrc, f_cw, bufQ + 32, 48, bufP, 16, nullptr, 0, nullptr,
       1.f, 0.f, 16, 16, 0);
  // tmp = L B + A
  spmm(stream, i_off, i_csrc, f_cw, bufQ + 16, 48, bufR, 16, bufQ, 48, nullptr,
       1.f, 1.f, 16, 16, 0);
  // H1 = relu(2 L D + tmp + b1) -> bufS (ld16)
  spmm(stream, i_off, i_csrc, f_cw, bufP, 16, bufS, 16, bufR, 16, b1,
       2.f, 1.f, 16, 16, 1);

  // ---- Layer 2 (standard): 16 -> 32, X = bufS ----
  gemm(stream, bufS, 16, W2, 32, nullptr, bufQ, 32, nullptr, 0, NN, 16, 0);
  spmm(stream, i_off, i_csrc, f_cw, bufS, 16, bufP, 16, nullptr, 0, nullptr,
       1.f, 0.f, 16, 16, 0);                                           // T1
  gemm(stream, bufP, 16, W2 + 16 * 32, 32, nullptr, bufQ, 32, bufQ, 32, NN, 16, 0);
  spmm(stream, i_off, i_csrc, f_cw, bufP, 16, bufR, 16, bufS, 16, nullptr,
       2.f, -1.f, 16, 16, 0);                                          // T2 = 2 L T1 - X
  gemm(stream, bufR, 16, W2 + 2 * 16 * 32, 32, b2, bufQ, 32, bufQ, 32, NN, 16, 1);
  // H2 = bufQ (ld32)

  // ---- Layer 3 (standard): 32 -> 64, X = bufQ ----
  gemm(stream, bufQ, 32, W3, 64, nullptr, bufS, 64, nullptr, 0, NN, 32, 0);
  spmm(stream, i_off, i_csrc, f_cw, bufQ, 32, bufP, 32, nullptr, 0, nullptr,
       1.f, 0.f, 32, 32, 0);
  gemm(stream, bufP, 32, W3 + 32 * 64, 64, nullptr, bufS, 64, bufS, 64, NN, 32, 0);
  spmm(stream, i_off, i_csrc, f_cw, bufP, 32, bufR, 32, bufQ, 32, nullptr,
       2.f, -1.f, 32, 32, 0);
  gemm(stream, bufR, 32, W3 + 2 * 32 * 64, 64, b3, bufS, 64, bufS, 64, NN, 32, 1);
  // H3 = bufS (ld64)

  // ---- Layer 4 (standard): 64 -> 128, X = bufS ----
  gemm(stream, bufS, 64, W4, 128, nullptr, bufQ, 128, nullptr, 0, NN, 64, 0);
  spmm(stream, i_off, i_csrc, f_cw, bufS, 64, bufP, 64, nullptr, 0, nullptr,
       1.f, 0.f, 64, 64, 0);
  gemm(stream, bufP, 64, W4 + 64 * 128, 128, nullptr, bufQ, 128, bufQ, 128, NN, 64, 0);
  spmm(stream, i_off, i_csrc, f_cw, bufP, 64, bufR, 64, bufS, 64, nullptr,
       2.f, -1.f, 64, 64, 0);
  gemm(stream, bufR, 64, W4 + 2 * 64 * 128, 128, b4, bufQ, 128, bufQ, 128, NN, 64, 1);
  // H4 = bufQ (ld128)

  // ---- Layer 5 (push-through): 128 -> 19 (padded 20), X = bufQ ----
  // ABC = X @ Wc5 -> bufS (ld60): A=+0, B=+20, C=+40 (pad cols are zero)
  gemm(stream, bufQ, 128, wc5, 60, nullptr, bufS, 60, nullptr, 0, NN, 128, 0);
  // D = L C
  spmm(stream, i_off, i_csrc, f_cw, bufS + 40, 60, bufP, 20, nullptr, 0, nullptr,
       1.f, 0.f, 20, 20, 0);
  // tmp = L B + A
  spmm(stream, i_off, i_csrc, f_cw, bufS + 20, 60, bufR, 20, bufS, 60, nullptr,
       1.f, 1.f, 20, 20, 0);
  // out = 2 L D + tmp + b5  (store ld19, 19 cols)
  spmm(stream, i_off, i_csrc, f_cw, bufP, 20, out, 19, bufR, 20, b5,
       2.f, 1.f, 20, 19, 0);

  softmax_kernel<<<(NN + 255) / 256, 256, 0, stream>>>(out, NN, 19);
}